// Round 8
// baseline (242.596 us; speedup 1.0000x reference)
//
#include <hip/hip_runtime.h>
#include <hip/hip_bf16.h>

#define DEV __device__ __forceinline__

typedef __attribute__((ext_vector_type(8))) short bf16x8;
typedef __attribute__((ext_vector_type(4))) float f32x4;
typedef __attribute__((ext_vector_type(16))) float f32x16;

// ---------- helpers ----------
DEV short f2bf(float x){ __hip_bfloat16 h = __float2bfloat16(x); return *(short*)&h; }
DEV unsigned pack2bf(float a, float b){
  return (unsigned)(unsigned short)f2bf(a) | ((unsigned)(unsigned short)f2bf(b) << 16);
}

// sigmoid-form tanh-GELU: x * sigmoid(2z), z = 0.7979(x + 0.0447 x^3)
DEV float gelu_fast(float x){
  float z = 0.7978845608028654f*(x + 0.044715f*x*x*x);
  float e = __expf(-2.f*z);
  return x / (1.f + e);
}

// dims
#define SB 4096
#define NT 16384   // B*S
#define DM 64

// ---------- weight convert+transpose: f32 [K][N] -> bf16 [N][K], 32x32 tiles ----------
__global__ __launch_bounds__(256) void wconv(
    const float* __restrict__ wq, const float* __restrict__ wk,
    const float* __restrict__ wv, const float* __restrict__ wo,
    const float* __restrict__ w1, const float* __restrict__ w2,
    short* __restrict__ wqT, short* __restrict__ wkT,
    short* __restrict__ wvT, short* __restrict__ woT,
    short* __restrict__ w1T, short* __restrict__ w2T)
{
  int t = blockIdx.x, l = blockIdx.y;
  const float* src; short* dst; int K, N, kt, nt;
  if (t < 16) {
    int m = t >> 2, sub = t & 3; kt = sub >> 1; nt = sub & 1; K = 64; N = 64;
    const float* s4[4] = {wq, wk, wv, wo};
    short*       d4[4] = {wqT, wkT, wvT, woT};
    src = s4[m] + l*4096; dst = d4[m] + l*4096;
  } else if (t < 48) {
    kt = (t-16) >> 4; nt = (t-16) & 15; K = 64; N = 512;
    src = w1 + l*32768; dst = w1T + l*32768;
  } else {
    kt = (t-48) >> 1; nt = (t-48) & 1; K = 512; N = 64;
    src = w2 + l*32768; dst = w2T + l*32768;
  }
  __shared__ float lds[32][33];
  int tx = threadIdx.x & 31, ty = threadIdx.x >> 5;
  int k0 = kt*32, n0 = nt*32;
  #pragma unroll
  for (int j=0;j<4;++j) lds[ty+8*j][tx] = src[(size_t)(k0+ty+8*j)*N + n0 + tx];
  __syncthreads();
  #pragma unroll
  for (int j=0;j<4;++j) {
    int nn = ty+8*j;
    dst[(size_t)(n0+nn)*K + k0 + tx] = f2bf(lds[tx][nn]);
  }
}

// ---------- fused building blocks ----------
DEV void make_frags_ln(const float* rowp, float mean, float inv,
    const float* __restrict__ s, const float* __restrict__ b, int kq,
    bf16x8& a0, bf16x8& a1){
  #pragma unroll
  for (int i=0;i<8;++i) a0[i] = f2bf((rowp[kq*8+i]-mean)*inv*s[kq*8+i]+b[kq*8+i]);
  #pragma unroll
  for (int i=0;i<8;++i) a1[i] = f2bf((rowp[32+kq*8+i]-mean)*inv*s[32+kq*8+i]+b[32+kq*8+i]);
}
// wave GEMM: 16 rows x 16 cols, K=64 (2 MFMA), B from bf16 [N][64] transposed weights.
DEV void gemm1(const bf16x8& a0, const bf16x8& a1, const short* __restrict__ WT,
               int col0, int kq, int r, f32x4& acc){
  const short* wp = WT + (size_t)(col0 + r)*64 + kq*8;
  bf16x8 b0  = *(const bf16x8*)(wp);
  bf16x8 b1v = *(const bf16x8*)(wp + 32);
  acc = __builtin_amdgcn_mfma_f32_16x16x32_bf16(a0, b0,  acc, 0, 0, 0);
  acc = __builtin_amdgcn_mfma_f32_16x16x32_bf16(a1, b1v, acc, 0, 0, 0);
}

// ---------- fused layer kernel v3: 16 rows/block, grid 1024, 4 blocks/CU ----------
// wave w owns 16-col tile w*16 for attnout/fc2/qkv; fc1: cols 128w..128w+127.
template<bool EMBED, bool LAST>
__global__ __launch_bounds__(256,4) void fused_kernel(
    const int* __restrict__ x, const float* __restrict__ emb,
    const unsigned short* __restrict__ ab,
    const short* __restrict__ woT, const float* __restrict__ bo,
    const float* __restrict__ ln2s, const float* __restrict__ ln2b,
    const short* __restrict__ w1T, const float* __restrict__ b1,
    const short* __restrict__ w2T, const float* __restrict__ b2,
    const float* __restrict__ lns, const float* __restrict__ lnb,   // LN1(next) or LNf
    const short* __restrict__ wqT, const short* __restrict__ wkT, const short* __restrict__ wvT,
    const float* __restrict__ bq, const float* __restrict__ bk, const float* __restrict__ bv,
    unsigned short* __restrict__ qo, unsigned short* __restrict__ ko, unsigned short* __restrict__ vo,
    float* __restrict__ h, float* __restrict__ part)
{
  __shared__ float hN[16][76];
  __shared__ short mid[16][520];
  __shared__ float mu[16], iv[16];

  const int bid = blockIdx.x;
  const int row_g0 = bid * 16;
  const int tid = threadIdx.x;
  const int w = tid >> 6, lane = tid & 63;
  const int r = lane & 15, kq = lane >> 4;
  const int wcol = w * 16;
  const int srow = tid >> 4, sdq = tid & 15;   // stats/embed: 16 threads/row, 4 dims each

  if constexpr (EMBED) {
    int tg = row_g0 + srow;
    int s = tg & (SB-1);
    int tok = x[tg];
    #pragma unroll
    for (int i=0;i<4;++i) {
      int d = sdq*4 + i;
      float fe = (float)(d & ~1) * (1.0f/64.0f);
      float invk = __expf(-9.210340371976184f * fe);
      float ang = (float)s * invk;
      float pe = (d & 1) ? __cosf(ang) : __sinf(ang);
      float val = emb[tok*DM + d] + pe;
      hN[srow][d] = val;
      h[(size_t)tg*DM + d] = val;
    }
  } else {
    // attn-out projection + residual
    const short* abp = (const short*)(ab + (size_t)(row_g0 + r)*DM + kq*8);
    bf16x8 a0 = *(const bf16x8*)abp;
    bf16x8 a1 = *(const bf16x8*)(abp + 32);
    f32x4 acc = (f32x4){0.f,0.f,0.f,0.f};
    gemm1(a0, a1, woT, wcol, kq, r, acc);
    int col = wcol + r;
    #pragma unroll
    for (int j=0;j<4;++j) {
      int rl = kq*4 + j;
      hN[rl][col] = acc[j] + bo[col] + h[(size_t)(row_g0+rl)*DM + col];
    }
  }
  __syncthreads();

  // LN stats (LN1 for EMBED, LN2 otherwise)
  {
    const float* p = &hN[srow][sdq*4];
    float v0=p[0], v1=p[1], v2=p[2], v3=p[3];
    float sum = v0+v1+v2+v3;
    sum += __shfl_xor(sum, 1, 64); sum += __shfl_xor(sum, 2, 64);
    sum += __shfl_xor(sum, 4, 64); sum += __shfl_xor(sum, 8, 64);
    float mean = sum * (1.f/64.f);
    float d0=v0-mean, d1=v1-mean, d2=v2-mean, d3=v3-mean;
    float sq = d0*d0+d1*d1+d2*d2+d3*d3;
    sq += __shfl_xor(sq, 1, 64); sq += __shfl_xor(sq, 2, 64);
    sq += __shfl_xor(sq, 4, 64); sq += __shfl_xor(sq, 8, 64);
    if (sdq == 0) { mu[srow] = mean; iv[srow] = rsqrtf(sq*(1.f/64.f) + 1e-6f); }
  }
  __syncthreads();

  if constexpr (!EMBED) {
    // ---- fc1: wave w covers cols [128w, 128w+128), all 16 rows ----
    bf16x8 a0, a1;
    make_frags_ln(&hN[r][0], mu[r], iv[r], ln2s, ln2b, kq, a0, a1);
    f32x4 acc1[8];
    #pragma unroll
    for (int ct=0; ct<8; ++ct) acc1[ct] = (f32x4){0.f,0.f,0.f,0.f};
    #pragma unroll
    for (int ct=0; ct<8; ++ct) {
      const short* wp = w1T + (size_t)(w*128 + ct*16 + r)*64 + kq*8;
      bf16x8 b0  = *(const bf16x8*)(wp);
      bf16x8 b1v = *(const bf16x8*)(wp + 32);
      acc1[ct] = __builtin_amdgcn_mfma_f32_16x16x32_bf16(a0, b0,  acc1[ct], 0, 0, 0);
      acc1[ct] = __builtin_amdgcn_mfma_f32_16x16x32_bf16(a1, b1v, acc1[ct], 0, 0, 0);
    }
    #pragma unroll
    for (int ct=0; ct<8; ++ct) {
      int col = w*128 + ct*16 + r;
      float bb = b1[col];
      #pragma unroll
      for (int j=0; j<4; ++j)
        mid[kq*4 + j][col] = f2bf(gelu_fast(acc1[ct][j] + bb));
    }
    __syncthreads();

    // ---- fc2: wave tile (16 rows x 16 cols), K=512 ----
    f32x4 acc2 = (f32x4){0.f,0.f,0.f,0.f};
    #pragma unroll
    for (int ks=0; ks<16; ++ks) {
      bf16x8 af = *(const bf16x8*)(&mid[r][ks*32 + kq*8]);
      const short* wp = w2T + (size_t)(wcol + r)*512 + ks*32 + kq*8;
      bf16x8 bw = *(const bf16x8*)(wp);
      acc2 = __builtin_amdgcn_mfma_f32_16x16x32_bf16(af, bw, acc2, 0, 0, 0);
    }
    {
      int col = wcol + r;
      float bb = b2[col];
      #pragma unroll
      for (int j=0; j<4; ++j) {
        int rl = kq*4 + j;
        float val = acc2[j] + bb + hN[rl][col];
        hN[rl][col] = val;
        h[(size_t)(row_g0+rl)*DM + col] = val;
      }
    }
    __syncthreads();

    // LN stats for LN1(next) / LNf
    {
      const float* p = &hN[srow][sdq*4];
      float v0=p[0], v1=p[1], v2=p[2], v3=p[3];
      float sum = v0+v1+v2+v3;
      sum += __shfl_xor(sum, 1, 64); sum += __shfl_xor(sum, 2, 64);
      sum += __shfl_xor(sum, 4, 64); sum += __shfl_xor(sum, 8, 64);
      float mean = sum * (1.f/64.f);
      float d0=v0-mean, d1=v1-mean, d2=v2-mean, d3=v3-mean;
      float sq = d0*d0+d1*d1+d2*d2+d3*d3;
      sq += __shfl_xor(sq, 1, 64); sq += __shfl_xor(sq, 2, 64);
      sq += __shfl_xor(sq, 4, 64); sq += __shfl_xor(sq, 8, 64);
      if (sdq == 0) { mu[srow] = mean; iv[srow] = rsqrtf(sq*(1.f/64.f) + 1e-6f); }
    }
    __syncthreads();
  }

  if constexpr (!LAST) {
    // qkv of (next) layer
    const float qscale = 0.35355339059327373f;  // 1/sqrt(8)
    bf16x8 a0, a1;
    make_frags_ln(&hN[r][0], mu[r], iv[r], lns, lnb, kq, a0, a1);
    f32x4 aq  = (f32x4){0.f,0.f,0.f,0.f};
    f32x4 akk = (f32x4){0.f,0.f,0.f,0.f};
    f32x4 av  = (f32x4){0.f,0.f,0.f,0.f};
    gemm1(a0, a1, wqT, wcol, kq, r, aq);
    gemm1(a0, a1, wkT, wcol, kq, r, akk);
    gemm1(a0, a1, wvT, wcol, kq, r, av);
    int col = wcol + r;
    float bqv = bq[col], bkv = bk[col], bvv = bv[col];
    #pragma unroll
    for (int j=0;j<4;++j) {
      size_t oi = (size_t)(row_g0 + kq*4 + j)*DM + col;
      qo[oi] = (unsigned short)f2bf((aq[j] + bqv)*qscale);
      ko[oi] = (unsigned short)f2bf(akk[j] + bkv);
      vo[oi] = (unsigned short)f2bf(av[j] + bvv);
    }
  } else {
    // final LN (in place) + pool partial (sum of 16 rows per dim)
    float mean = mu[srow], inv = iv[srow];
    #pragma unroll
    for (int i=0;i<4;++i) {
      int d = sdq*4 + i;
      hN[srow][d] = (hN[srow][d]-mean)*inv*lns[d] + lnb[d];
    }
    __syncthreads();
    if (tid < 64) {
      float s = 0.f;
      #pragma unroll 4
      for (int rr=0; rr<16; ++rr) s += hN[rr][tid];
      part[bid*64 + tid] = s;
    }
  }
}

// ---------- sliding-window attention (MFMA) ----------
#define VSTR 664
__global__ __launch_bounds__(256) void attn_kernel(
    const unsigned short* __restrict__ qg_,
    const unsigned short* __restrict__ kg_,
    const unsigned short* __restrict__ vg_,
    __hip_bfloat16* __restrict__ out)
{
  const int qblk = blockIdx.x, bh = blockIdx.y;
  const int b = bh >> 3, hh = bh & 7;
  const int tid = threadIdx.x;
  const int q0b = qblk << 7;
  const int kbase = q0b - 256;

  __shared__ unsigned short Ks[640*8];
  __shared__ unsigned short Vs[8*VSTR];

  const unsigned short* kgp = kg_ + ((size_t)b*SB)*DM + hh*8;
  const unsigned short* vgp = vg_ + ((size_t)b*SB)*DM + hh*8;

  for (int e = tid; e < 640; e += 256) {
    int g = kbase + e;
    uint4 kv = make_uint4(0,0,0,0), vv = make_uint4(0,0,0,0);
    if ((unsigned)g < (unsigned)SB) {
      kv = *(const uint4*)(kgp + (size_t)g*DM);
      vv = *(const uint4*)(vgp + (size_t)g*DM);
    }
    *(uint4*)(Ks + e*8) = kv;
    const unsigned short* pv = (const unsigned short*)&vv;
    #pragma unroll
    for (int d = 0; d < 8; ++d) Vs[d*VSTR + e] = pv[d];
  }
  __syncthreads();

  const int w = tid >> 6;
  const int lane = tid & 63;
  const int qc = lane & 31;
  const int hf = lane >> 5;
  const int qglob = q0b + 32*w + qc;

  bf16x8 qfrag = {};
  if (hf == 0) qfrag = *(const bf16x8*)(qg_ + ((size_t)b*SB + qglob)*DM + hh*8);

  f32x16 oacc = {};
  float lacc = 0.f;

  for (int t = 0; t <= 16; ++t) {
    const int k0l = 32*w + 32*t;
    const int k0g = kbase + k0l;
    if (k0g > SB-1 || k0g + 31 < 0) continue;

    bf16x8 kfrag = {};
    if (hf == 0) kfrag = *(const bf16x8*)(Ks + (k0l + qc)*8);

    f32x16 s = __builtin_amdgcn_mfma_f32_32x32x16_bf16(kfrag, qfrag, (f32x16){}, 0, 0, 0);

    float p[16];
    bool needmask = (t == 0) | (t == 16) | (k0g < 0) | (k0g + 31 > SB-1);
    if (needmask) {
      #pragma unroll
      for (int rr = 0; rr < 16; ++rr) {
        int klg = k0g + (rr&3) + 8*(rr>>2) + 4*hf;
        bool ok = ((unsigned)(klg - qglob + 256) <= 512u) && ((unsigned)klg < (unsigned)SB);
        p[rr] = ok ? __expf(s[rr]) : 0.f;
      }
    } else {
      #pragma unroll
      for (int rr = 0; rr < 16; ++rr) p[rr] = __expf(s[rr]);
    }
    #pragma unroll
    for (int rr = 0; rr < 16; ++rr) lacc += p[rr];

    unsigned pk[8];
    #pragma unroll
    for (int j = 0; j < 8; ++j) pk[j] = pack2bf(p[2*j], p[2*j+1]);
    unsigned sw[8];
    #pragma unroll
    for (int j = 0; j < 8; ++j) sw[j] = __shfl_xor(pk[j], 32, 64);

    union { unsigned u[4]; bf16x8 v; } b1;
    b1.u[0] = hf ? sw[2] : pk[0];
    b1.u[1] = hf ? sw[3] : pk[1];
    b1.u[2] = hf ? pk[2] : sw[0];
    b1.u[3] = hf ? pk[3] : sw[1];
    bf16x8 va1 = {};
    if (qc < 8) va1 = *(const bf16x8*)(Vs + qc*VSTR + k0l + 8*hf);
    oacc = __builtin_amdgcn_mfma_f32_32x32x16_bf16(va1, b1.v, oacc, 0, 0, 0);

    union { unsigned u[4]; bf16x8 v; } b2;
    b2.u[0] = hf ? sw[6] : pk[4];
    b2.u[1] = hf ? sw[7] : pk[5];
    b2.u[2] = hf ? pk[6] : sw[4];
    b2.u[3] = hf ? pk[7] : sw[5];
    bf16x8 va2 = {};
    if (qc < 8) va2 = *(const bf16x8*)(Vs + qc*VSTR + k0l + 16 + 8*hf);
    oacc = __builtin_amdgcn_mfma_f32_32x32x16_bf16(va2, b2.v, oacc, 0, 0, 0);
  }

  float lsum = lacc + __shfl_xor(lacc, 32, 64);
  float rcp = 1.f / lsum;
  unsigned short ov[4];
  #pragma unroll
  for (int j = 0; j < 4; ++j) ov[j] = (unsigned short)f2bf(oacc[j] * rcp);
  *(uint2*)(out + ((size_t)b*SB + qglob)*DM + hh*8 + 4*hf) = *(uint2*)ov;
}

// ---------- pool finalize + classifier ----------
__global__ __launch_bounds__(256) void pool_finalize(const float* __restrict__ part,
    const float* __restrict__ wcls, const float* __restrict__ bcls, float* __restrict__ out)
{
  int tid = threadIdx.x;
  int b = tid >> 6, d = tid & 63;
  float sum = 0.f;
  #pragma unroll 8
  for (int i = 0; i < 256; ++i) sum += part[(b*256 + i)*64 + d];
  __shared__ float pooled[4][64];
  pooled[b][d] = sum * (1.f/4096.f);
  __syncthreads();
  if (tid < 40) {
    int bb = tid / 10, c = tid % 10;
    float acc = bcls[c];
    #pragma unroll
    for (int dd = 0; dd < 64; ++dd) acc = fmaf(pooled[bb][dd], wcls[dd*10 + c], acc);
    out[tid] = acc;
  }
}

// ---------- launcher ----------
extern "C" void kernel_launch(void* const* d_in, const int* in_sizes, int n_in,
                              void* d_out, int out_size, void* d_ws, size_t ws_size,
                              hipStream_t stream)
{
  const int*   x    = (const int*)d_in[0];
  const float* emb  = (const float*)d_in[1];
  const float* wq   = (const float*)d_in[2];
  const float* bq   = (const float*)d_in[3];
  const float* wk   = (const float*)d_in[4];
  const float* bk   = (const float*)d_in[5];
  const float* wv   = (const float*)d_in[6];
  const float* bv   = (const float*)d_in[7];
  const float* wo   = (const float*)d_in[8];
  const float* bo   = (const float*)d_in[9];
  const float* ln1s = (const float*)d_in[10];
  const float* ln1b = (const float*)d_in[11];
  const float* ln2s = (const float*)d_in[12];
  const float* ln2b = (const float*)d_in[13];
  const float* w1   = (const float*)d_in[14];
  const float* b1   = (const float*)d_in[15];
  const float* w2   = (const float*)d_in[16];
  const float* b2   = (const float*)d_in[17];
  const float* lnfs = (const float*)d_in[18];
  const float* lnfb = (const float*)d_in[19];
  const float* wcls = (const float*)d_in[20];
  const float* bcls = (const float*)d_in[21];
  float* out = (float*)d_out;

  char* wsb = (char*)d_ws;
  const size_t MB = 1u << 20;
  float* h  = (float*)(wsb);                             // 4 MB f32 [16384][64]
  unsigned short* qb2 = (unsigned short*)(wsb + 4*MB);   // 2 MB bf16
  unsigned short* kb2 = (unsigned short*)(wsb + 6*MB);
  unsigned short* vb2 = (unsigned short*)(wsb + 8*MB);
  __hip_bfloat16* ab  = (__hip_bfloat16*)(wsb + 10*MB);  // 2 MB bf16
  short* wqT = (short*)(wsb + 12*MB);
  short* wkT = (short*)(wsb + 12*MB + 32*1024);
  short* wvT = (short*)(wsb + 12*MB + 64*1024);
  short* woT = (short*)(wsb + 12*MB + 96*1024);
  short* w1T = (short*)(wsb + 12*MB + 128*1024);         // 256 KB
  short* w2T = (short*)(wsb + 12*MB + 384*1024);         // 256 KB
  float* part = (float*)(wsb + 13*MB);                   // 256 KB

  wconv<<<dim3(80,4),256,0,stream>>>(wq,wk,wv,wo,w1,w2, wqT,wkT,wvT,woT,w1T,w2T);

  // head: embed + LN1(l0) + qkv(l0)
  fused_kernel<true,false><<<1024,256,0,stream>>>(
      x, emb, nullptr,
      nullptr, nullptr, nullptr, nullptr,
      nullptr, nullptr, nullptr, nullptr,
      ln1s, ln1b,
      wqT, wkT, wvT, bq, bk, bv,
      qb2, kb2, vb2, h, nullptr);

  for (int l = 0; l < 4; ++l) {
    attn_kernel<<<dim3(32,32),256,0,stream>>>(qb2, kb2, vb2, ab);
    if (l < 3) {
      fused_kernel<false,false><<<1024,256,0,stream>>>(
          nullptr, nullptr, (const unsigned short*)ab,
          woT+4096*l, bo+64*l, ln2s+64*l, ln2b+64*l,
          w1T+32768*l, b1+512*l, w2T+32768*l, b2+64*l,
          ln1s+64*(l+1), ln1b+64*(l+1),
          wqT+4096*(l+1), wkT+4096*(l+1), wvT+4096*(l+1),
          bq+64*(l+1), bk+64*(l+1), bv+64*(l+1),
          qb2, kb2, vb2, h, nullptr);
    } else {
      fused_kernel<false,true><<<1024,256,0,stream>>>(
          nullptr, nullptr, (const unsigned short*)ab,
          woT+4096*l, bo+64*l, ln2s+64*l, ln2b+64*l,
          w1T+32768*l, b1+512*l, w2T+32768*l, b2+64*l,
          lnfs, lnfb,
          nullptr, nullptr, nullptr, nullptr, nullptr, nullptr,
          nullptr, nullptr, nullptr, h, part);
    }
  }
  pool_finalize<<<1,256,0,stream>>>(part, wcls, bcls, out);
}